// Round 2
// baseline (305.876 us; speedup 1.0000x reference)
//
#include <hip/hip_runtime.h>
#include <hip/hip_bf16.h>

// LinearSim: out = X @ W.T + Bias  (normalizations in the reference cancel).
// M=65536 tokens, K=512 in_features, N=512 out_features. f32 in/out,
// bf16 MFMA inside (error ~4e-3 << 5.25e-2 threshold).

typedef __bf16 bf16x8 __attribute__((ext_vector_type(8)));
typedef float  f32x4  __attribute__((ext_vector_type(4)));

constexpr int M_TOK = 65536;
constexpr int K_IN  = 512;
constexpr int N_OUT = 512;

constexpr int BM = 128, BN = 128, BK = 32;
constexpr int PK = BK + 8;   // padded LDS row: 40 bf16 = 80 B (conflict-free, 16B-aligned)

__global__ __launch_bounds__(256, 2)
void linear_sim_kernel(const float* __restrict__ X,
                       const float* __restrict__ W,
                       const float* __restrict__ Bias,
                       float* __restrict__ Out)
{
    __shared__ __bf16 As[BM][PK];
    __shared__ __bf16 Bs[BN][PK];

    const int bid = blockIdx.x;
    const int nb  = bid & 3;        // 4 N-tiles fastest -> sibling blocks share X tile via L3
    const int mb  = bid >> 2;       // 512 M-tiles
    const int m0 = mb * BM, n0 = nb * BN;

    const int tid  = threadIdx.x;
    const int lane = tid & 63;
    const int wave = tid >> 6;      // 0..3
    const int wm = wave >> 1;       // 2x2 wave grid; wave tile 64x64
    const int wn = wave & 1;

    // staging: thread t loads 16 consecutive K-floats of row (t>>1), half (t&1)
    const int srow = tid >> 1;           // 0..127
    const int sk   = (tid & 1) * 16;     // 0 or 16

    const float* Xp = X + (size_t)(m0 + srow) * K_IN + sk;
    const float* Wp = W + (size_t)(n0 + srow) * K_IN + sk;

    f32x4 acc[16];
    const f32x4 zero = {0.f, 0.f, 0.f, 0.f};
    #pragma unroll
    for (int i = 0; i < 16; ++i) acc[i] = zero;

    const int l15 = lane & 15;
    const int lg  = lane >> 4;

    for (int k0 = 0; k0 < K_IN; k0 += BK) {
        // -------- global loads (f32) --------
        f32x4 xa[4], wb[4];
        #pragma unroll
        for (int q = 0; q < 4; ++q) xa[q] = *(const f32x4*)(Xp + k0 + q * 4);
        #pragma unroll
        for (int q = 0; q < 4; ++q) wb[q] = *(const f32x4*)(Wp + k0 + q * 4);

        __syncthreads();   // previous iter's LDS reads complete before overwrite

        // -------- convert f32 -> bf16, write LDS (2x b128 each for A and B) --------
        #pragma unroll
        for (int h = 0; h < 2; ++h) {
            bf16x8 ta, tb;
            #pragma unroll
            for (int q = 0; q < 2; ++q)
                #pragma unroll
                for (int e = 0; e < 4; ++e) {
                    ta[q * 4 + e] = (__bf16)xa[h * 2 + q][e];
                    tb[q * 4 + e] = (__bf16)wb[h * 2 + q][e];
                }
            *(bf16x8*)&As[srow][sk + h * 8] = ta;
            *(bf16x8*)&Bs[srow][sk + h * 8] = tb;
        }

        __syncthreads();

        // -------- fragments + MFMA --------
        // A frag: row = l&15, k = (l>>4)*8 + e ; B frag symmetric (both K-contig)
        bf16x8 af[4], bfr[4];
        #pragma unroll
        for (int i = 0; i < 4; ++i)
            af[i] = *(const bf16x8*)&As[wm * 64 + i * 16 + l15][lg * 8];
        #pragma unroll
        for (int i = 0; i < 4; ++i)
            bfr[i] = *(const bf16x8*)&Bs[wn * 64 + i * 16 + l15][lg * 8];

        #pragma unroll
        for (int mi = 0; mi < 4; ++mi)
            #pragma unroll
            for (int ni = 0; ni < 4; ++ni)
                acc[mi * 4 + ni] = __builtin_amdgcn_mfma_f32_16x16x32_bf16(
                    af[mi], bfr[ni], acc[mi * 4 + ni], 0, 0, 0);
    }

    // -------- epilogue: C/D layout col = lane&15, row = (lane>>4)*4 + reg --------
    #pragma unroll
    for (int ni = 0; ni < 4; ++ni) {
        const int col = n0 + wn * 64 + ni * 16 + l15;
        const float bv = Bias[col];
        #pragma unroll
        for (int mi = 0; mi < 4; ++mi) {
            const int row0 = m0 + wm * 64 + mi * 16 + lg * 4;
            f32x4 a = acc[mi * 4 + ni];
            #pragma unroll
            for (int r = 0; r < 4; ++r)
                Out[(size_t)(row0 + r) * N_OUT + col] = a[r] + bv;
        }
    }
}

extern "C" void kernel_launch(void* const* d_in, const int* in_sizes, int n_in,
                              void* d_out, int out_size, void* d_ws, size_t ws_size,
                              hipStream_t stream) {
    const float* X    = (const float*)d_in[0];
    const float* W    = (const float*)d_in[1];
    const float* Bias = (const float*)d_in[2];
    float* Out        = (float*)d_out;

    dim3 grid((M_TOK / BM) * (N_OUT / BN));   // 512 * 4 = 2048 blocks
    linear_sim_kernel<<<grid, dim3(256), 0, stream>>>(X, W, Bias, Out);
}